// Round 6
// baseline (79.787 us; speedup 1.0000x reference)
//
#include <hip/hip_runtime.h>
#include <hip/hip_bf16.h>
#include <math.h>

// Causal + key-padding-mask attention, MFMA bf16, BARRIER-FREE per-wave flash.
// (N=64, T=1024, D=64) fp32 in/out.
//  - 512 blocks x 4 INDEPENDENT waves (no __syncthreads). Wave = one 32-row
//    q-strip; per-wave LDS slice: K[64][144B] + V^T[64][144B] + kadd, single-
//    buffered; wave-local WAR ordering via s_waitcnt lgkmcnt(0) before overwrite.
//  - strips per block: {g, 31-g, 15-g, 16+g} -> constant 34 tiles/block; rotated
//    by head&3 to decorrelate SIMD pairing. All blocks resident (2/CU) at t=0.
//  - QK^T swapped: S^T = mfma(A=K, B=Q^T) -> lane = q col; scores lane-local.
//  - PV swapped:   O^T = mfma(A=V^T, B=P^T) -> lane = q col; stats lane-local.
//  - exp2-domain softmax; defer-rescale (THR=8); l-sum halves combined once.

#define N_HEADS 64
#define T_SEQ   1024
#define D_HEAD  64
#define KVB     64
#define PADDING_NUM (-4294967295.0f)      // -2^32 + 1
#define KSTRIDE 144
#define VSTRIDE 144
#define QSCALE  (0.125f * 1.4426950408889634f)   // 1/sqrt(64) * log2(e)
#define RESCALE_THR 8.0f
#define KBYTES  (KVB * KSTRIDE)           // 9216
#define VBYTES  (D_HEAD * VSTRIDE)        // 9216
#define WAVE_LDS (KBYTES + VBYTES + 256)  // + kadd(256B) = 18688 B/wave

#define LGKM0 asm volatile("s_waitcnt lgkmcnt(0)" ::: "memory")

typedef __attribute__((ext_vector_type(8)))  short bf16x8;
typedef __attribute__((ext_vector_type(16))) float f32x16;
typedef __attribute__((ext_vector_type(4)))  unsigned int uint4v;

union FragU { uint4v u; bf16x8 v; };
union F4U  { float4 f; uint4v u; };

template<bool B> struct BoolC { static constexpr bool value = B; };

static __device__ __forceinline__ unsigned pk2(float lo, float hi) {   // v_cvt_pk_bf16_f32
    union { __hip_bfloat162 h2; unsigned u; } c;
    c.h2 = __float22bfloat162_rn(make_float2(lo, hi));
    return c.u;
}
static __device__ __forceinline__ f32x16 zero16() {
    f32x16 z;
    #pragma unroll
    for (int i = 0; i < 16; ++i) z[i] = 0.f;
    return z;
}

__global__ __launch_bounds__(256, 2)
void attn_fwd(const float* __restrict__ q, const float* __restrict__ k,
              const float* __restrict__ v, float* __restrict__ out) {
    __shared__ __align__(16) char lds[4][WAVE_LDS];   // 74752 B -> 2 blocks/CU

    const int bx  = blockIdx.x;
    const int n   = bx & 63;
    const int g   = bx >> 6;                 // 0..7
    const int tid = threadIdx.x;
    const int w   = tid >> 6;
    const int l   = tid & 63;
    const int h   = l >> 5;
    const int ql  = l & 31;

    // wave -> strip (32 rows): balanced quad {g, 31-g, 15-g, 16+g}, head-rotated
    const int widx = (w + (n & 3)) & 3;
    const int sp   = (widx == 0) ? g : (widx == 1) ? (31 - g)
                   : (widx == 2) ? (15 - g) : (16 + g);
    const int qrow = sp * 32 + ql;
    const int nt   = (sp >> 1) + 1;          // 64-key tiles up to diagonal

    char*  Kl    = lds[w];
    char*  Vt    = lds[w] + KBYTES;
    float* kaddL = (float*)(lds[w] + KBYTES + VBYTES);

    const float* qg = q + (size_t)n * T_SEQ * D_HEAD;
    const float* kg = k + (size_t)n * T_SEQ * D_HEAD;
    const float* vg = v + (size_t)n * T_SEQ * D_HEAD;

    // ---- Q^T B-frags: lane = q col (ql), dims s*16 + h*8 + e, exp2-domain ----
    FragU qf[4];
    #pragma unroll
    for (int s = 0; s < 4; ++s) {
        const float* qp = qg + (size_t)qrow * D_HEAD + s * 16 + h * 8;
        float4 a = ((const float4*)qp)[0], b = ((const float4*)qp)[1];
        qf[s].u[0] = pk2(a.x * QSCALE, a.y * QSCALE);
        qf[s].u[1] = pk2(a.z * QSCALE, a.w * QSCALE);
        qf[s].u[2] = pk2(b.x * QSCALE, b.y * QSCALE);
        qf[s].u[3] = pk2(b.z * QSCALE, b.w * QSCALE);
    }

    f32x16 O0 = zero16(), O1 = zero16();
    float mx = -INFINITY, lsum = 0.f;        // lsum per h-half; combined at end

    // ---- per-wave staging (lane owns K row l; V row-pair 2ql/2ql+1, h-dims) ----
    float4 kb[16], vb[16];
    auto k_issue = [&](int t) {
        const float4* p = (const float4*)(kg + (size_t)t * KVB * D_HEAD + l * D_HEAD);
        #pragma unroll
        for (int i = 0; i < 16; ++i) kb[i] = p[i];
    };
    auto k_write = [&]() {
        LGKM0;                               // tile-t LDS reads retired (WAR-safe)
        unsigned ob = 0u;                    // exact pad mask: OR of |bits|
        #pragma unroll
        for (int i = 0; i < 16; ++i) {
            F4U c; c.f = kb[i];
            ob |= c.u[0] | c.u[1] | c.u[2] | c.u[3];
        }
        kaddL[l] = ((ob & 0x7fffffffu) != 0u) ? 0.f : PADDING_NUM;
        #pragma unroll
        for (int o = 0; o < 8; ++o) {
            uint4v w4;
            w4[0] = pk2(kb[2*o].x,   kb[2*o].y);
            w4[1] = pk2(kb[2*o].z,   kb[2*o].w);
            w4[2] = pk2(kb[2*o+1].x, kb[2*o+1].y);
            w4[3] = pk2(kb[2*o+1].z, kb[2*o+1].w);
            *(uint4v*)(Kl + l * KSTRIDE + o * 16) = w4;
        }
    };
    auto v_issue = [&](int t) {
        const float* base = vg + (size_t)t * KVB * D_HEAD + (size_t)(2 * ql) * D_HEAD + 32 * h;
        #pragma unroll
        for (int i = 0; i < 8; ++i) {
            vb[i]     = ((const float4*)base)[i];
            vb[i + 8] = ((const float4*)(base + D_HEAD))[i];
        }
    };
    auto v_write = [&]() {
        LGKM0;                               // tile-t PV reads retired
        #pragma unroll
        for (int i = 0; i < 8; ++i) {
            const int d0 = 32 * h + 4 * i;
            float4 A = vb[i], B = vb[i + 8]; // keys 2ql, 2ql+1
            *(unsigned*)(Vt + (d0 + 0) * VSTRIDE + ql * 4) = pk2(A.x, B.x);
            *(unsigned*)(Vt + (d0 + 1) * VSTRIDE + ql * 4) = pk2(A.y, B.y);
            *(unsigned*)(Vt + (d0 + 2) * VSTRIDE + ql * 4) = pk2(A.z, B.z);
            *(unsigned*)(Vt + (d0 + 3) * VSTRIDE + ql * 4) = pk2(A.w, B.w);
        }
    };

    // ---- QK^T + mask + online softmax (S -> P in place) ----
    auto qk_soft = [&](f32x16 (&S)[2], int t, auto causal_c) {
        constexpr bool CAUSAL = decltype(causal_c)::value;
        #pragma unroll
        for (int kgi = 0; kgi < 2; ++kgi) {
            f32x16 acc = zero16();
            #pragma unroll
            for (int s = 0; s < 4; ++s) {
                bf16x8 kf = *(const bf16x8*)(Kl + (kgi * 32 + ql) * KSTRIDE + s * 32 + h * 16);
                acc = __builtin_amdgcn_mfma_f32_32x32x16_bf16(kf, qf[s].v, acc, 0, 0, 0);
            }
            S[kgi] = acc;
        }
        float tm[4] = {-INFINITY, -INFINITY, -INFINITY, -INFINITY};
        #pragma unroll
        for (int kgi = 0; kgi < 2; ++kgi) {
            #pragma unroll
            for (int rq = 0; rq < 4; ++rq) {
                float4 kd = *(const float4*)&kaddL[kgi * 32 + rq * 8 + 4 * h];
                #pragma unroll
                for (int j = 0; j < 4; ++j) {
                    int r = rq * 4 + j;
                    float sc = S[kgi][r] + ((const float*)&kd)[j];
                    if (CAUSAL) {
                        int key = t * KVB + kgi * 32 + rq * 8 + 4 * h + j;
                        sc = (key <= qrow) ? sc : PADDING_NUM;
                    }
                    S[kgi][r] = sc;
                    tm[rq] = fmaxf(tm[rq], sc);
                }
            }
        }
        float tmax = fmaxf(fmaxf(tm[0], tm[1]), fmaxf(tm[2], tm[3]));
        tmax = fmaxf(tmax, __shfl_xor(tmax, 32));

        if (!__all(tmax <= mx + RESCALE_THR)) {   // defer-rescale (T13)
            const float newm = fmaxf(mx, tmax);
            const float corr = __builtin_amdgcn_exp2f(mx - newm);
            mx = newm;
            lsum *= corr;
            #pragma unroll
            for (int i = 0; i < 16; ++i) { O0[i] *= corr; O1[i] *= corr; }
        }
        float ls = 0.f;
        #pragma unroll
        for (int kgi = 0; kgi < 2; ++kgi)
            #pragma unroll
            for (int r = 0; r < 16; ++r) {
                float pv = __builtin_amdgcn_exp2f(S[kgi][r] - mx);  // bounded by 2^THR
                S[kgi][r] = pv;
                ls += pv;
            }
        lsum += ls;
    };

    // ---- PV: O^T += mfma(A=V^T, B=P^T); P^T frag via pack + half swap ----
    auto pv_acc = [&](f32x16 (&S)[2]) {
        #pragma unroll
        for (int kgi = 0; kgi < 2; ++kgi) {
            #pragma unroll
            for (int s2 = 0; s2 < 2; ++s2) {
                unsigned A0 = pk2(S[kgi][8 * s2 + 0], S[kgi][8 * s2 + 1]);
                unsigned A1 = pk2(S[kgi][8 * s2 + 2], S[kgi][8 * s2 + 3]);
                unsigned A2 = pk2(S[kgi][8 * s2 + 4], S[kgi][8 * s2 + 5]);
                unsigned A3 = pk2(S[kgi][8 * s2 + 6], S[kgi][8 * s2 + 7]);
                unsigned sw0 = (unsigned)__shfl_xor((int)A0, 32);
                unsigned sw1 = (unsigned)__shfl_xor((int)A1, 32);
                unsigned sw2 = (unsigned)__shfl_xor((int)A2, 32);
                unsigned sw3 = (unsigned)__shfl_xor((int)A3, 32);
                FragU pb;
                pb.u[0] = h ? sw2 : A0;
                pb.u[1] = h ? sw3 : A1;
                pb.u[2] = h ? A2 : sw0;
                pb.u[3] = h ? A3 : sw1;
                const int ksf = kgi * 2 + s2;
                bf16x8 vf0 = *(const bf16x8*)(Vt + (0 * 32 + ql) * VSTRIDE + ksf * 32 + h * 16);
                bf16x8 vf1 = *(const bf16x8*)(Vt + (1 * 32 + ql) * VSTRIDE + ksf * 32 + h * 16);
                O0 = __builtin_amdgcn_mfma_f32_32x32x16_bf16(vf0, pb.v, O0, 0, 0, 0);
                O1 = __builtin_amdgcn_mfma_f32_32x32x16_bf16(vf1, pb.v, O1, 0, 0, 0);
            }
        }
    };

    // ---- prologue: stage tile 0 (wave-local, no barrier) ----
    k_issue(0); v_issue(0);
    k_write();  v_write();

    // ---- main loop: loads for t+1 fly over compute of t ----
    for (int t = 0; t < nt; ++t) {
        const bool more = (t + 1 < nt);
        if (more) k_issue(t + 1);
        f32x16 S[2];
        if (t == nt - 1) qk_soft(S, t, BoolC<true>{});
        else             qk_soft(S, t, BoolC<false>{});
        if (more) { k_write(); v_issue(t + 1); }   // K regs die at write
        pv_acc(S);
        if (more) v_write();
    }

    // ---- epilogue: combine h-halves of l; O^T rows d = crow + 32g ----
    const float ltot = lsum + __shfl_xor(lsum, 32);
    const float inv  = 1.f / ltot;
    float* op = out + ((size_t)n * T_SEQ + qrow) * D_HEAD;
    #pragma unroll
    for (int gg = 0; gg < 2; ++gg) {
        #pragma unroll
        for (int q2 = 0; q2 < 4; ++q2) {
            const int d0 = 8 * q2 + 4 * h + 32 * gg;
            float4 t4;
            t4.x = (gg ? O1[4*q2+0] : O0[4*q2+0]) * inv;
            t4.y = (gg ? O1[4*q2+1] : O0[4*q2+1]) * inv;
            t4.z = (gg ? O1[4*q2+2] : O0[4*q2+2]) * inv;
            t4.w = (gg ? O1[4*q2+3] : O0[4*q2+3]) * inv;
            *(float4*)(op + d0) = t4;
        }
    }
}

extern "C" void kernel_launch(void* const* d_in, const int* in_sizes, int n_in,
                              void* d_out, int out_size, void* d_ws, size_t ws_size,
                              hipStream_t stream) {
    (void)d_ws; (void)ws_size; (void)in_sizes; (void)n_in; (void)out_size;
    const float* q = (const float*)d_in[0];
    const float* k = (const float*)d_in[1];
    const float* v = (const float*)d_in[2];
    float* o = (float*)d_out;
    dim3 grid(N_HEADS * 8);   // 512 blocks x 4 independent waves = 2048 waves
    dim3 block(256);
    hipLaunchKernelGGL(attn_fwd, grid, block, 0, stream, q, k, v, o);
}